// Round 1
// baseline (594.573 us; speedup 1.0000x reference)
//
#include <hip/hip_runtime.h>
#include <hip/hip_bf16.h>

#define B_    16
#define CIN   64
#define COUT  64
#define ZD    64
#define WHID  32
#define TT    32768
#define KK    128
#define SS    256

// ---------------------------------------------------------------------------
// K0: tap-sum of wm2: wm2s[j][h] = sum_t wm2[(t*4096+j)*32+h], j<4096, h<32
// ---------------------------------------------------------------------------
__global__ void k_tapsum(const float* __restrict__ wm2, float* __restrict__ wm2s) {
    int i = blockIdx.x * 256 + threadIdx.x;
    if (i < 4096 * 32)
        wm2s[i] = wm2[i] + wm2[i + 131072] + wm2[i + 262144];
}

// ---------------------------------------------------------------------------
// K1: per-segment hypernet hidden h (stored) and bias (stored).
// 256 blocks x 256 threads; block handles 8 segments, 32 threads each.
// ---------------------------------------------------------------------------
__global__ __launch_bounds__(256) void k_hyper_small(
    const float* __restrict__ z,
    const float* __restrict__ wm1, const float* __restrict__ wb1,
    const float* __restrict__ bm1, const float* __restrict__ bb1,
    const float* __restrict__ bm2, const float* __restrict__ bb2,
    float* __restrict__ ws_h, float* __restrict__ ws_bias)
{
    __shared__ float hb[8][32];
    const int tid = threadIdx.x;
    const int seg = tid >> 5, w = tid & 31;
    const int bk = blockIdx.x * 8 + seg;
    const int b = bk >> 7, k = bk & 127;
    const float* zp = z + b * ZD * KK + k;

    float hv = wb1[w], hbv = bb1[w];
    #pragma unroll
    for (int zz = 0; zz < 64; ++zz) {
        float zv = zp[zz * KK];
        hv  += wm1[w * 64 + zz] * zv;
        hbv += bm1[w * 64 + zz] * zv;
    }
    hv  = fmaxf(hv, 0.f);
    hbv = fmaxf(hbv, 0.f);
    ws_h[bk * 32 + w] = hv;
    hb[seg][w] = hbv;
    __syncthreads();

    #pragma unroll
    for (int t = 0; t < 2; ++t) {
        int o = w + t * 32;
        float acc = bb2[o];
        #pragma unroll
        for (int hh = 0; hh < 32; ++hh)
            acc += bm2[o * 32 + hh] * hb[seg][hh];
        ws_bias[bk * 64 + o] = acc;
    }
}

// ---------------------------------------------------------------------------
// K2: w_eff GEMM: ws_w[bk][j] = wm2s[j][:] @ h[bk][:] + tap-summed wb2[j]
// 128 blocks x 256 threads; wave handles 4 segments with h in registers.
// ---------------------------------------------------------------------------
__global__ __launch_bounds__(256) void k_weff(
    const float* __restrict__ wm2s, const float* __restrict__ wb2,
    const float* __restrict__ ws_h, float* __restrict__ ws_w)
{
    const int tid = threadIdx.x;
    const int wave = tid >> 6, lane = tid & 63;
    const int bk0 = blockIdx.x * 16 + wave * 4;

    float hreg[4][32];
    #pragma unroll
    for (int q = 0; q < 4; ++q) {
        #pragma unroll
        for (int hh = 0; hh < 32; ++hh)
            hreg[q][hh] = ws_h[(bk0 + q) * 32 + hh];
    }

    for (int jj = 0; jj < 64; ++jj) {
        int j = jj * 64 + lane;
        float4 row[8];
        const float4* rp = (const float4*)(wm2s + j * 32);
        #pragma unroll
        for (int q = 0; q < 8; ++q) row[q] = rp[q];
        float wb = wb2[j] + wb2[j + 4096] + wb2[j + 8192];
        const float* rowf = (const float*)row;
        #pragma unroll
        for (int q = 0; q < 4; ++q) {
            float acc = wb;
            #pragma unroll
            for (int hh = 0; hh < 32; ++hh)
                acc += rowf[hh] * hreg[q][hh];
            ws_w[(size_t)(bk0 + q) * 4096 + j] = acc;
        }
    }
}

// ---------------------------------------------------------------------------
// K3: fused main kernel. 1 block per (b,k) segment, 256 threads.
// Phase 1: y = sin(x_tile @ W + bias), y -> LDS (bf16).
// Phase 2: res = (rw@y + rb + x)/2, skip = sw@y + sb.
// LDS: U = 32KB union (W | rwT+swT) + ybuf 32KB = exactly 64KB.
// ---------------------------------------------------------------------------
__global__ __launch_bounds__(256, 2) void k_main(
    const float* __restrict__ x,
    const float* __restrict__ ws_w, const float* __restrict__ ws_bias,
    const float* __restrict__ rw, const float* __restrict__ rb,
    const float* __restrict__ sw, const float* __restrict__ sb,
    float* __restrict__ out)
{
    __shared__ float U[8192];                 // 32 KB
    __shared__ unsigned short ybuf[64][256];  // 32 KB (bf16)

    const int tid = threadIdx.x;
    const int bk = blockIdx.x;
    const int b = bk >> 7, k = bk & 127;
    const int tbase = k * SS;
    const int sg = tid & 63, og = tid >> 6;
    const int s0 = sg * 4, o0 = og * 16;
    float4* U4 = (float4*)U;

    // ---- stage W (4096 floats) into U[0..4095]; bias into U[4096..4159] ----
    {
        const float4* Wg = (const float4*)(ws_w + (size_t)bk * 4096);
        #pragma unroll
        for (int r = 0; r < 4; ++r) U4[tid + 256 * r] = Wg[tid + 256 * r];
        if (tid < 64) U[4096 + tid] = ws_bias[bk * 64 + tid];
    }
    __syncthreads();

    // ---- phase 1: y = sin(x @ W + bias) ----
    float acc[4][16];
    #pragma unroll
    for (int e = 0; e < 4; ++e)
        #pragma unroll
        for (int v = 0; v < 16; ++v) acc[e][v] = 0.f;

    const float* xs = x + (size_t)b * CIN * TT + tbase + s0;
    #pragma unroll 8
    for (int i = 0; i < 64; ++i) {
        float4 xv = *(const float4*)(xs + (size_t)i * TT);
        #pragma unroll
        for (int q = 0; q < 4; ++q) {
            float4 wq = U4[i * 16 + og * 4 + q];
            float wv[4] = {wq.x, wq.y, wq.z, wq.w};
            #pragma unroll
            for (int e2 = 0; e2 < 4; ++e2) {
                acc[0][q * 4 + e2] += xv.x * wv[e2];
                acc[1][q * 4 + e2] += xv.y * wv[e2];
                acc[2][q * 4 + e2] += xv.z * wv[e2];
                acc[3][q * 4 + e2] += xv.w * wv[e2];
            }
        }
    }
    #pragma unroll
    for (int v = 0; v < 16; ++v) {
        int o = o0 + v;
        float bo = U[4096 + o];
        unsigned int us[4];
        #pragma unroll
        for (int e = 0; e < 4; ++e) {
            float yv = __sinf(acc[e][v] + bo);
            unsigned int u = __float_as_uint(yv);
            u += 0x7fffu + ((u >> 16) & 1u);   // RNE to bf16
            us[e] = u >> 16;
        }
        uint2 pk;
        pk.x = us[0] | (us[1] << 16);
        pk.y = us[2] | (us[3] << 16);
        *(uint2*)&ybuf[o][s0] = pk;
    }
    __syncthreads();

    // ---- stage rw^T into U[0..4095], sw^T into U[4096..8191] ----
    #pragma unroll
    for (int r = 0; r < 16; ++r) {
        int e = tid + 256 * r;
        int o = e >> 6, c = e & 63;
        U[c * 64 + o]        = rw[e];
        U[4096 + c * 64 + o] = sw[e];
    }
    __syncthreads();

    // ---- phase 2: res/skip = (rw|sw) @ y ----
    float ar[4][16], asx[4][16];
    #pragma unroll
    for (int e = 0; e < 4; ++e)
        #pragma unroll
        for (int v = 0; v < 16; ++v) { ar[e][v] = 0.f; asx[e][v] = 0.f; }

    #pragma unroll 4
    for (int c = 0; c < 64; ++c) {
        uint2 yu = *(const uint2*)&ybuf[c][s0];
        float yv[4];
        yv[0] = __uint_as_float(yu.x << 16);
        yv[1] = __uint_as_float(yu.x & 0xffff0000u);
        yv[2] = __uint_as_float(yu.y << 16);
        yv[3] = __uint_as_float(yu.y & 0xffff0000u);
        #pragma unroll
        for (int q = 0; q < 4; ++q) {
            float4 rq = U4[c * 16 + og * 4 + q];
            float4 sq = U4[1024 + c * 16 + og * 4 + q];
            float rv[4] = {rq.x, rq.y, rq.z, rq.w};
            float sv[4] = {sq.x, sq.y, sq.z, sq.w};
            #pragma unroll
            for (int e2 = 0; e2 < 4; ++e2) {
                #pragma unroll
                for (int e = 0; e < 4; ++e) {
                    ar[e][q * 4 + e2]  += yv[e] * rv[e2];
                    asx[e][q * 4 + e2] += yv[e] * sv[e2];
                }
            }
        }
    }

    // ---- epilogue ----
    float* resp = out;
    float* skpp = out + (size_t)B_ * COUT * TT;
    #pragma unroll
    for (int v = 0; v < 16; ++v) {
        int o = o0 + v;
        size_t off = (size_t)(b * COUT + o) * TT + tbase + s0;
        float4 xo = *(const float4*)(x + off);
        float rbv = rb[o], sbv = sb[o];
        float4 ro, so;
        ro.x = (ar[0][v] + rbv + xo.x) * 0.5f;
        ro.y = (ar[1][v] + rbv + xo.y) * 0.5f;
        ro.z = (ar[2][v] + rbv + xo.z) * 0.5f;
        ro.w = (ar[3][v] + rbv + xo.w) * 0.5f;
        so.x = asx[0][v] + sbv;
        so.y = asx[1][v] + sbv;
        so.z = asx[2][v] + sbv;
        so.w = asx[3][v] + sbv;
        *(float4*)(resp + off) = ro;
        *(float4*)(skpp + off) = so;
    }
}

// ---------------------------------------------------------------------------
extern "C" void kernel_launch(void* const* d_in, const int* in_sizes, int n_in,
                              void* d_out, int out_size, void* d_ws, size_t ws_size,
                              hipStream_t stream) {
    const float* x   = (const float*)d_in[0];
    const float* z   = (const float*)d_in[1];
    const float* wm1 = (const float*)d_in[2];
    const float* wb1 = (const float*)d_in[3];
    const float* wm2 = (const float*)d_in[4];
    const float* wb2 = (const float*)d_in[5];
    const float* bm1 = (const float*)d_in[6];
    const float* bb1 = (const float*)d_in[7];
    const float* bm2 = (const float*)d_in[8];
    const float* bb2 = (const float*)d_in[9];
    const float* rw  = (const float*)d_in[10];
    const float* rb  = (const float*)d_in[11];
    const float* sw  = (const float*)d_in[12];
    const float* sb  = (const float*)d_in[13];
    float* out = (float*)d_out;

    float* ws      = (float*)d_ws;
    float* ws_wm2s = ws;             // 131072 floats
    float* ws_h    = ws + 131072;    // 65536 floats
    float* ws_bias = ws + 196608;    // 131072 floats
    float* ws_w    = ws + 327680;    // 8388608 floats

    hipLaunchKernelGGL(k_tapsum, dim3(512), dim3(256), 0, stream, wm2, ws_wm2s);
    hipLaunchKernelGGL(k_hyper_small, dim3(256), dim3(256), 0, stream,
                       z, wm1, wb1, bm1, bb1, bm2, bb2, ws_h, ws_bias);
    hipLaunchKernelGGL(k_weff, dim3(128), dim3(256), 0, stream,
                       ws_wm2s, wb2, ws_h, ws_w);
    hipLaunchKernelGGL(k_main, dim3(2048), dim3(256), 0, stream,
                       x, ws_w, ws_bias, rw, rb, sw, sb, out);
}